// Round 13
// baseline (118.586 us; speedup 1.0000x reference)
//
#include <hip/hip_runtime.h>
#include <stdint.h>

// All FP must match XLA's HLO op-for-op: no mul+add contraction.
#pragma clang fp contract(off)

typedef unsigned long long u64;
typedef uint32_t u32;

#define M_PROP 200000u
#define N_GT   128u
#define NM     25600000u

// priority keep-windows (23-bit priorities):
//  B: pos pairs (iou>0.4, ~500k) with m1 >= 2^23-2^15 -> E~1953 kept ==> the
//     true top-128 pos-priority keys are all kept (exact).
//  C: neg pairs (iou<0.1, ~25.1M) with m3 >= 2^23-2^10 -> E~3065 kept.
#define BCUT 8355840u   // 2^23 - 2^15
#define CCUT 8387584u   // 2^23 - 1024
#define CCUT_RAW 0xFFF80000u  // CCUT<<9; (a^b)>=this <=> ((a^b)>>9)>=CCUT
#define IB_POS 0x3ECCCCCDu  // float bits of 0.4f; ib > this <=> iou > 0.4f

#define SHARDS 16u
#define SHARD_CAP 4096u
#define ACAP_SHARD 65536u
#define TOPA_CAP 8192u
#define COMP_CAP 8192u
#define ALIST 512u         // per-wave A-precandidate LDS staging (u32 idx)

#define NBX 782u           // ceil(200000/256)
#define NT_C (NBX * 4u)    // C tiles: 32 gt-rows each (issued FIRST)
#define NT_ALL (NBX * 6u)  // + A tiles: 64 gt-rows each
#define PERSIST 2048u      // 8 blocks/CU x 256 CUs

// counter slots, each padded to 256B to spread L2 atomic traffic:
// 0..15=C shards, 16..31=B shards, 32..47=A shards, 48=cntTopA, 56=ticket
#define CSLOT(i) counters[(u32)(i) * 64u]

__device__ inline u32 rotl32(u32 x, u32 r) { return __builtin_rotateleft32(x, r); }

// prefix count of set bits below this lane (2 VALU ops)
__device__ inline u32 lane_prefix(u64 mask) {
  return __builtin_amdgcn_mbcnt_hi((u32)(mask >> 32),
                                   __builtin_amdgcn_mbcnt_lo((u32)mask, 0u));
}

// ---------------- threefry2x32 (20 rounds) ----------------
__host__ __device__ inline void tf2x32(u32 k0, u32 k1, u32 x0, u32 x1,
                                       u32& o0, u32& o1) {
  u32 ks0 = k0, ks1 = k1, ks2 = k0 ^ k1 ^ 0x1BD11BDAu;
  x0 += ks0; x1 += ks1;
#ifdef __HIP_DEVICE_COMPILE__
#define TF_R(r) { x0 += x1; x1 = rotl32(x1, r); x1 ^= x0; }
#else
#define TF_R(r) { x0 += x1; x1 = (x1 << r) | (x1 >> (32 - r)); x1 ^= x0; }
#endif
  TF_R(13) TF_R(15) TF_R(26) TF_R(6)
  x0 += ks1; x1 += ks2 + 1u;
  TF_R(17) TF_R(29) TF_R(16) TF_R(24)
  x0 += ks2; x1 += ks0 + 2u;
  TF_R(13) TF_R(15) TF_R(26) TF_R(6)
  x0 += ks0; x1 += ks1 + 3u;
  TF_R(17) TF_R(29) TF_R(16) TF_R(24)
  x0 += ks1; x1 += ks2 + 4u;
  TF_R(13) TF_R(15) TF_R(26) TF_R(6)
  x0 += ks2; x1 += ks0 + 5u;
#undef TF_R
  o0 = x0; o1 = x1;
}

// partitionable threefry: 32 bits for element idx
__device__ inline u32 jax_bits32(u32 ka, u32 kb, u32 idx) {
  u32 a, b; tf2x32(ka, kb, 0u, idx, a, b);
  return a ^ b;
}

static void jax_split3(u32& k1a, u32& k1b, u32& k2a, u32& k2b,
                       u32& k3a, u32& k3b) {
  const u32 K0 = 0u, K1 = 42u;
  tf2x32(K0, K1, 0u, 0u, k1a, k1b);
  tf2x32(K0, K1, 0u, 1u, k2a, k2b);
  tf2x32(K0, K1, 0u, 2u, k3a, k3b);
}

// wave-aggregated append (one atomic per wave per predicate)
__device__ inline u32 wave_append_slot(u32* ctr, bool pred, bool& any) {
  u64 mask = __ballot(pred);
  if (mask == 0ull) { any = false; return 0u; }
  any = true;
  u32 prefix = lane_prefix(mask);
  int leader = __ffsll(mask) - 1;
  u32 base = 0u;
  if ((int)(threadIdx.x & 63u) == leader)
    base = atomicAdd(ctr, (u32)__popcll(mask));
  base = __shfl(base, leader, 64);
  return base + prefix;
}

__device__ inline u32 iouBin(u32 bits) {  // monotone bins over (0.25, 1.0]
  u32 b = (bits - 0x3E800000u) >> 14;
  return b > 1023u ? 1023u : b;
}

// ---------------- K1: persistent ticket-scheduled collection ----------------
// tickets 0..NT_C-1: C-role (32 gt rows, threefry-heavy, issued first)
// tickets NT_C..NT_ALL-1: A-role (64 gt rows, IoU-heavy)
__global__ __launch_bounds__(256, 8) void rpn_collect(
    const float4* __restrict__ props, const float4* __restrict__ gt,
    u64* __restrict__ bufA, u64* __restrict__ bufB, u64* __restrict__ bufC,
    u32* __restrict__ counters, u32* __restrict__ gHistA,
    u32 k1a, u32 k1b, u32 k3a, u32 k3b) {
  __shared__ float4 gtS[64];
  __shared__ float gtAreaS[64];
  __shared__ u32 hA[1024];
  __shared__ u32 listA[4][ALIST];
  __shared__ u32 s_tile;
  const u32 tid = threadIdx.x;
  const u32 lane = tid & 63u;
  const u32 wid = tid >> 6;
  for (u32 i = tid; i < 1024u; i += 256u) hA[i] = 0u;

  const u32 ks0 = k3a, ks1 = k3b, ks2 = k3a ^ k3b ^ 0x1BD11BDAu;
  const u32 i1 = ks2 + 1u, i2 = ks0 + 2u, i3 = ks1 + 3u;
  const u32 i4 = ks2 + 4u, i5 = ks0 + 5u;

  for (;;) {
    __syncthreads();  // protect gtS/hA/s_tile reuse across tiles
    if (tid == 0u) s_tile = atomicAdd(&CSLOT(56), 1u);
    __syncthreads();
    const u32 t = s_tile;
    if (t >= NT_ALL) break;
    const u32 shard = t & (SHARDS - 1u);

    if (t < NT_C) {
      // ======== C-role: 8-chain round-interleaved threefry scan ========
      const u32 bx = t >> 2;
      const u32 gbase = (t & 3u) * 32u;
      for (u32 j = tid; j < 32u; j += 256u) {
        float4 gb = gt[gbase + j];
        gtS[j] = gb;
        gtAreaS[j] = (gb.z - gb.x) * (gb.w - gb.y);
      }
      __syncthreads();
      u32* cntC_g = &CSLOT(shard);
      u64* myBufC = bufC + (size_t)shard * SHARD_CAP;

      u32 p = bx * 256u + tid;
      bool active = p < M_PROP;

      for (u32 gg = 0u; gg < 32u; gg += 8u) {
        const u32 ibase = (gbase + gg) * M_PROP + p;
        // init 8 chains: x0=ks0 (ctr0=0), x1 = ctr1 + ks1
#define ALL8(OP) OP(0) OP(1) OP(2) OP(3) OP(4) OP(5) OP(6) OP(7)
#define TFI(i) u32 x0_##i = ks0, x1_##i = (ibase + (i) * M_PROP) + ks1;
        ALL8(TFI)
#undef TFI
        // round r applied across ALL chains before round r+1 -> forced ILP
#define TFR0(i) x0_##i += x1_##i; x1_##i = rotl32(x1_##i, RT); x1_##i ^= x0_##i;
#define RND(rot) { const u32 RT = rot; ALL8(TFR0) }
#define INJ(a, b) { ALL8(TFJ) }
#define TFJ(i) x0_##i += KA; x1_##i += KB;
        { const u32 KA = 0u; (void)KA; }  // (pattern anchor; no-op)
        RND(13) RND(15) RND(26) RND(6)
        { const u32 KA = ks1, KB = i1; ALL8(TFJ) }
        RND(17) RND(29) RND(16) RND(24)
        { const u32 KA = ks2, KB = i2; ALL8(TFJ) }
        RND(13) RND(15) RND(26) RND(6)
        { const u32 KA = ks0, KB = i3; ALL8(TFJ) }
        RND(17) RND(29) RND(16) RND(24)
        { const u32 KA = ks1, KB = i4; ALL8(TFJ) }
        RND(13) RND(15) RND(26) RND(6)
        { const u32 KA = ks2, KB = i5; ALL8(TFJ) }
#undef TFJ
#undef INJ
#undef RND
#undef TFR0
#define TFO(i) const u32 ab_##i = x0_##i ^ x1_##i;
        ALL8(TFO)
#undef TFO
        bool pre0 = ab_0 >= CCUT_RAW, pre1 = ab_1 >= CCUT_RAW;
        bool pre2 = ab_2 >= CCUT_RAW, pre3 = ab_3 >= CCUT_RAW;
        bool pre4 = ab_4 >= CCUT_RAW, pre5 = ab_5 >= CCUT_RAW;
        bool pre6 = ab_6 >= CCUT_RAW, pre7 = ab_7 >= CCUT_RAW;
        bool anyp = pre0 | pre1 | pre2 | pre3 | pre4 | pre5 | pre6 | pre7;
        if (__ballot(anyp)) {  // rare: ~6% of groups -> lazy exact IoU
          float4 pbx = make_float4(0.f, 0.f, 0.f, 0.f);
          if (active) pbx = props[p];
          float pax = (pbx.z - pbx.x) * (pbx.w - pbx.y);
#define CRARE(R)                                                             \
          {                                                                  \
            float4 gb = gtS[gg + (R)];                                       \
            float ga = gtAreaS[gg + (R)];                                    \
            float wx = fminf(gb.z, pbx.z) - fmaxf(gb.x, pbx.x);              \
            float wy = fminf(gb.w, pbx.w) - fmaxf(gb.y, pbx.y);              \
            wx = fmaxf(wx, 0.0f); wy = fmaxf(wy, 0.0f);                      \
            float inter = wx * wy;                                           \
            float iouX = inter / (ga + pax - inter);                         \
            bool cc = active && pre##R && (iouX < 0.1f);                     \
            bool any_;                                                       \
            u32 s = wave_append_slot(cntC_g, cc, any_);                      \
            if (cc && s < SHARD_CAP)                                         \
              myBufC[s] = ((u64)(ab_##R >> 9) << 25) |                       \
                          (u64)(0x1FFFFFFu - (ibase + (R) * M_PROP));        \
          }
          CRARE(0) CRARE(1) CRARE(2) CRARE(3)
          CRARE(4) CRARE(5) CRARE(6) CRARE(7)
#undef CRARE
        }
#undef ALL8
      }
    } else {
      // ================= A-role: IoU + A/B collection =================
      const u32 u = t - NT_C;
      const u32 bx = u >> 1;
      const u32 gbase = (u & 1u) * 64u;
      for (u32 j = tid; j < 64u; j += 256u) {
        float4 gb = gt[gbase + j];
        gtS[j] = gb;
        gtAreaS[j] = (gb.z - gb.x) * (gb.w - gb.y);
      }
      __syncthreads();
      u32* cntB_g = &CSLOT(16u + shard);
      u32* cntA_g = &CSLOT(32u + shard);
      u64* myBufB = bufB + (size_t)shard * SHARD_CAP;
      u64* myBufA = bufA + (size_t)shard * ACAP_SHARD;

      u32 p = bx * 256u + tid;
      bool active = p < M_PROP;
      float4 pb = make_float4(0.f, 0.f, 0.f, 0.f);
      if (active) pb = props[p];
      float pa = (pb.z - pb.x) * (pb.w - pb.y);
      u32 cntA = 0u;  // wave-uniform

#define PROCESS_A()                                                          \
      {                                                                      \
        for (u32 i = lane; i < cntA; i += 64u) {                             \
          u32 aidx = listA[wid][i];                                          \
          u32 row = aidx / M_PROP;                                           \
          u32 col = aidx - row * M_PROP;                                     \
          float4 pbx = props[col];                                           \
          float4 gbx = gtS[row - gbase];                                     \
          float gax = gtAreaS[row - gbase];                                  \
          float pax = (pbx.z - pbx.x) * (pbx.w - pbx.y);                     \
          float wxx = fminf(gbx.z, pbx.z) - fmaxf(gbx.x, pbx.x);             \
          float wyy = fminf(gbx.w, pbx.w) - fmaxf(gbx.y, pbx.y);             \
          wxx = fmaxf(wxx, 0.0f); wyy = fmaxf(wyy, 0.0f);                    \
          float interx = wxx * wyy;                                          \
          float ioux = interx / (gax + pax - interx);                        \
          u32 ib = __float_as_uint(ioux);                                    \
          bool isA = ioux > 0.25f;                                           \
          if (isA) atomicAdd(&hA[iouBin(ib)], 1u);                           \
          bool anyk;                                                         \
          u32 sk = wave_append_slot(cntA_g, isA, anyk);                      \
          if (isA && sk < ACAP_SHARD)                                        \
            myBufA[sk] = ((u64)ib << 25) | (u64)(0x1FFFFFFu - aidx);         \
          u32 m1 = jax_bits32(k1a, k1b, aidx) >> 9;                          \
          bool keep = isA && (ib > IB_POS) && (m1 >= BCUT);                  \
          bool anyb;                                                         \
          u32 sb2 = wave_append_slot(cntB_g, keep, anyb);                    \
          if (keep && sb2 < SHARD_CAP)                                       \
            myBufB[sb2] = ((u64)m1 << 25) | (u64)(0x1FFFFFFu - (aidx + 128u)); \
        }                                                                    \
        cntA = 0u;                                                           \
      }

      for (u32 gg = 0u; gg < 64u; gg += 4u) {
        bool aa[4];
#pragma unroll
        for (u32 r = 0u; r < 4u; ++r) {
          float4 gb = gtS[gg + r];
          float ga = gtAreaS[gg + r];
          float wx = fminf(gb.z, pb.z) - fmaxf(gb.x, pb.x);
          float wy = fminf(gb.w, pb.w) - fmaxf(gb.y, pb.y);
          wx = fmaxf(wx, 0.0f); wy = fmaxf(wy, 0.0f);
          float inter = wx * wy;
          float uni = ga + pa - inter;
          // conservative superset of iou>0.25 (margin 4e-5 >> fdiv ulp);
          // exact test re-done in PROCESS_A
          aa[r] = active && (inter > 0.2499f * uni);
        }
#pragma unroll
        for (u32 r = 0u; r < 4u; ++r) {
          u64 ma = __ballot(aa[r]);
          if (ma) {
            u32 pfx = lane_prefix(ma);
            if (aa[r]) listA[wid][cntA + pfx] = (gbase + gg + r) * M_PROP + p;
            cntA += (u32)__popcll(ma);
          }
        }
        if (cntA > ALIST - 256u) PROCESS_A();
      }
      PROCESS_A();
#undef PROCESS_A
    }
  }

  __syncthreads();
  for (u32 b = tid; b < 1024u; b += 256u) {
    u32 v = hA[b];
    if (v) atomicAdd(&gHistA[b], v);
  }
}

// ---------------- K2: per-wave shfl cut + filter stored A-keys ----------------
__global__ __launch_bounds__(256) void rpn_filterA(
    const u64* __restrict__ bufA, const u32* __restrict__ gHistA,
    u32* __restrict__ counters, u64* __restrict__ bufTopA) {
  const u32 tid = threadIdx.x;
  const u32 lane = tid & 63u;
  // each wave redundantly computes cut = max b with suffix(hist[b..]) >= 128
  u32 loc[16]; u32 t = 0u;
  const u32 bbase = lane * 16u;
#pragma unroll
  for (u32 j = 0u; j < 16u; ++j) { loc[j] = gHistA[bbase + j]; t += loc[j]; }
  u32 suf = t;
  for (u32 off = 1u; off < 64u; off <<= 1u) {
    u32 o = __shfl_down(suf, off, 64);
    if (lane + off < 64u) suf += o;
  }
  u32 cum = suf - t;   // sum over lanes > this one
  u32 cand = 0u; bool found = false;
#pragma unroll
  for (int j = 15; j >= 0; --j) {
    cum += loc[j];
    if (!found && cum >= 128u) { cand = bbase + (u32)j; found = true; }
  }
  for (u32 off = 1u; off < 64u; off <<= 1u) {
    u32 o = __shfl_xor(cand, off, 64);
    cand = o > cand ? o : cand;
  }
  const u32 cut = cand;
  // 256 blocks = 16 shards x 16 chunks, coalesced within each block
  const u32 sh = blockIdx.x & (SHARDS - 1u);
  const u32 chunk = blockIdx.x >> 4;
  u32 n = CSLOT(32u + sh); n = n < ACAP_SHARD ? n : ACAP_SHARD;
  const u64* sb = bufA + (size_t)sh * ACAP_SHARD;
  for (u32 i = chunk * 256u + tid; i < n; i += 16u * 256u) {
    u64 k = sb[i];
    bool keep = iouBin((u32)(k >> 25)) >= cut;
    bool any;
    u32 s = wave_append_slot(&CSLOT(48), keep, any);
    if (keep && s < TOPA_CAP) bufTopA[s] = k;
  }
}

// ---------------- K3: rank-select + loss ----------------
// 8-slot exact top-128 (desc) of nc distinct keys, nc <= 8192.
__device__ inline void rank_select(const u64* cand, u32 nc, u64* selKey) {
  const u32 tid = threadIdx.x;
  if (tid < 128u) selKey[tid] = 0ull;
  u64 k[8]; u32 r[8];
#pragma unroll
  for (int j = 0; j < 8; ++j) {
    u32 i = tid + (u32)j * 1024u;
    k[j] = (i < nc) ? cand[i] : 0ull;
    r[j] = 0u;
  }
  __syncthreads();
  for (u32 i = 0u; i < nc; ++i) {
    u64 v = cand[i];
#pragma unroll
    for (int j = 0; j < 8; ++j) r[j] += (v > k[j]) ? 1u : 0u;
  }
#pragma unroll
  for (int j = 0; j < 8; ++j) {
    u32 i = tid + (u32)j * 1024u;
    if (i < nc && r[j] < 128u) selKey[r[j]] = k[j];
  }
  __syncthreads();
}

// 1-slot exact top-128 of nc distinct keys, nc <= 1024.
__device__ inline void rank_select2(const u64* cand, u32 nc, u64* selKey) {
  const u32 tid = threadIdx.x;
  if (tid < 128u) selKey[tid] = 0ull;
  u64 mine = (tid < nc) ? cand[tid] : 0ull;
  __syncthreads();
  u32 r = 0u;
  for (u32 i = 0u; i < nc; ++i) r += (cand[i] > mine) ? 1u : 0u;
  if (tid < nc && r < 128u) selKey[r] = mine;
  __syncthreads();
}

__device__ inline float sl1(float d) {
  float ad = fabsf(d);
  return (ad < 1.0f) ? 0.5f * d * d : ad - 0.5f;
}

__global__ __launch_bounds__(1024) void rpn_finalize(
    const float* __restrict__ obj, const float4* __restrict__ props,
    const float4* __restrict__ gt,
    const u64* __restrict__ bufTopA,
    const u64* __restrict__ bufB, const u64* __restrict__ bufC,
    const u32* __restrict__ counters, float* __restrict__ out,
    u32 k2a, u32 k2b) {
  __shared__ u64 keyBuf[COMP_CAP];
  __shared__ u64 keyBuf2[1024];
  __shared__ u64 selKey[128];
  __shared__ u32 bestIdx[128];
  __shared__ u32 hist64[64];
  __shared__ float pr[16];
  __shared__ u32 s_cnt, s_cnt2, s_cutLo;
  __shared__ float s_reg, s_bcep;

  const u32 tid = threadIdx.x;
  const u32 lane = tid & 63u;
  const u32 wid = tid >> 6u;

  // ===== Phase 1: best_idx = top-128 of flat IoU (desc, ties idx asc) =====
  u32 nT = CSLOT(48); nT = nT < TOPA_CAP ? nT : TOPA_CAP;
  for (u32 i = tid; i < nT; i += 1024u) keyBuf[i] = bufTopA[i];
  __syncthreads();
  if (nT <= 1024u) rank_select2(keyBuf, nT, selKey);
  else rank_select(keyBuf, nT, selKey);
  if (tid < 128u) {
    u64 k = selKey[tid];
    bestIdx[tid] = (k == 0ull) ? 0u : (0x1FFFFFFu - (u32)(k & 0x1FFFFFFu));
  }
  __syncthreads();

  // ===== Phase 2: positives = top-128 of [best_prio(128) ++ pos_prio] =====
  if (tid == 0u) { s_cnt = 128u; s_cnt2 = 0u; }
  if (tid < 64u) hist64[tid] = 0u;
  __syncthreads();
  if (tid < 128u) {
    u32 m2 = jax_bits32(k2a, k2b, tid) >> 9;
    keyBuf[tid] = ((u64)m2 << 25) | (u64)(0x1FFFFFFu - tid);
    if (m2 >= BCUT) atomicAdd(&hist64[(m2 - BCUT) >> 9], 1u);
  }
  {  // wave-parallel shard load: wave w owns shard w
    u32 n = CSLOT(16u + wid); n = n < SHARD_CAP ? n : SHARD_CAP;
    const u64* sb = bufB + (size_t)wid * SHARD_CAP;
    for (u32 i = lane; i < n; i += 64u) {
      u64 k = sb[i];
      bool any;
      u32 s = wave_append_slot(&s_cnt, true, any);
      if (s < COMP_CAP) keyBuf[s] = k;
      atomicAdd(&hist64[((u32)(k >> 25) - BCUT) >> 9], 1u);
    }
  }
  __syncthreads();
  u32 nc = s_cnt < COMP_CAP ? s_cnt : COMP_CAP;
  if (wid == 0u) {  // single-wave 64-bin suffix cut, no barriers
    u32 suf = hist64[lane];
    for (u32 off = 1u; off < 64u; off <<= 1u) {
      u32 o = __shfl_down(suf, off, 64);
      if (lane + off < 64u) suf += o;
    }
    u64 ok = __ballot(suf >= 128u);
    u32 cutLo = 0u;
    if (ok) cutLo = BCUT + ((63u - (u32)__clzll(ok)) << 9);
    if (lane == 0u) s_cutLo = cutLo;
  }
  __syncthreads();
  {
    u64 cutKey = ((u64)s_cutLo) << 25;
    for (u32 i = tid; i < nc; i += 1024u) {
      u64 k = keyBuf[i];
      if (k >= cutKey) {
        u32 s = atomicAdd(&s_cnt2, 1u);
        if (s < 1024u) keyBuf2[s] = k;
      }
    }
  }
  __syncthreads();
  u32 ns = s_cnt2;
  if (ns <= 1024u) rank_select2(keyBuf2, ns, selKey);
  else rank_select(keyBuf, nc, selKey);

  float locReg = 0.0f, locBce = 0.0f;
  if (tid < 128u) {
    u64 k = selKey[tid];
    if (k != 0ull) {
      u32 c = 0x1FFFFFFu - (u32)(k & 0x1FFFFFFu);
      u32 pair = (c < 128u) ? bestIdx[c] : (c - 128u);
      if (pair < NM) {
        u32 row = pair / M_PROP, col = pair % M_PROP;
        float4 prb = props[col];
        float4 gb = gt[row];
        locReg = sl1(prb.x - gb.x) + sl1(prb.y - gb.y) +
                 sl1(prb.z - gb.z) + sl1(prb.w - gb.w);
        float l = obj[col];
        locBce = fmaxf(l, 0.0f) - l + log1pf(expf(-fabsf(l)));
      }
    }
  }
  {  // shfl reductions (only waves 0-1 carry data)
    float v = locReg;
    for (u32 off = 32u; off > 0u; off >>= 1u) v += __shfl_xor(v, off, 64);
    if (lane == 0u) pr[wid] = v;
    __syncthreads();
    if (tid == 0u) {
      float s = 0.0f;
#pragma unroll
      for (u32 w = 0u; w < 16u; ++w) s += pr[w];
      s_reg = s;
    }
    __syncthreads();
    v = locBce;
    for (u32 off = 32u; off > 0u; off >>= 1u) v += __shfl_xor(v, off, 64);
    if (lane == 0u) pr[wid] = v;
    __syncthreads();
    if (tid == 0u) {
      float s = 0.0f;
#pragma unroll
      for (u32 w = 0u; w < 16u; ++w) s += pr[w];
      s_bcep = s;
    }
    __syncthreads();
  }

  // ===== Phase 3: negatives = top-128 of neg_prio =====
  if (tid == 0u) { s_cnt = 0u; s_cnt2 = 0u; }
  if (tid < 64u) hist64[tid] = 0u;
  __syncthreads();
  {  // wave-parallel shard load
    u32 n = CSLOT(wid); n = n < SHARD_CAP ? n : SHARD_CAP;
    const u64* sb = bufC + (size_t)wid * SHARD_CAP;
    for (u32 i = lane; i < n; i += 64u) {
      u64 k = sb[i];
      bool any;
      u32 s = wave_append_slot(&s_cnt, true, any);
      if (s < COMP_CAP) keyBuf[s] = k;
      atomicAdd(&hist64[((u32)(k >> 25) - CCUT) >> 4], 1u);
    }
  }
  __syncthreads();
  nc = s_cnt < COMP_CAP ? s_cnt : COMP_CAP;
  if (wid == 0u) {
    u32 suf = hist64[lane];
    for (u32 off = 1u; off < 64u; off <<= 1u) {
      u32 o = __shfl_down(suf, off, 64);
      if (lane + off < 64u) suf += o;
    }
    u64 ok = __ballot(suf >= 128u);
    u32 cutLo = 0u;
    if (ok) cutLo = CCUT + ((63u - (u32)__clzll(ok)) << 4);
    if (lane == 0u) s_cutLo = cutLo;
  }
  __syncthreads();
  {
    u64 cutKey = ((u64)s_cutLo) << 25;
    for (u32 i = tid; i < nc; i += 1024u) {
      u64 k = keyBuf[i];
      if (k >= cutKey) {
        u32 s = atomicAdd(&s_cnt2, 1u);
        if (s < 1024u) keyBuf2[s] = k;
      }
    }
  }
  __syncthreads();
  ns = s_cnt2;
  if (ns <= 1024u) rank_select2(keyBuf2, ns, selKey);
  else rank_select(keyBuf, nc, selKey);

  float locBceN = 0.0f;
  if (tid < 128u) {
    u64 k = selKey[tid];
    if (k != 0ull) {
      u32 idx = 0x1FFFFFFu - (u32)(k & 0x1FFFFFFu);
      u32 col = idx % M_PROP;
      float l = obj[col];
      locBceN = fmaxf(l, 0.0f) + log1pf(expf(-fabsf(l)));
    }
  }
  {
    float v = locBceN;
    for (u32 off = 32u; off > 0u; off >>= 1u) v += __shfl_xor(v, off, 64);
    if (lane == 0u) pr[wid] = v;
    __syncthreads();
    if (tid == 0u) {
      float s = 0.0f;
#pragma unroll
      for (u32 w = 0u; w < 16u; ++w) s += pr[w];
      float cls = (s_bcep + s) / 256.0f;
      float reg = s_reg / 512.0f;
      out[0] = cls + 10.0f * reg;
    }
  }
}

extern "C" void kernel_launch(void* const* d_in, const int* in_sizes, int n_in,
                              void* d_out, int out_size, void* d_ws, size_t ws_size,
                              hipStream_t stream) {
  (void)in_sizes; (void)n_in; (void)out_size; (void)ws_size;
  const float* obj = (const float*)d_in[0];
  const float4* props = (const float4*)d_in[1];
  const float4* gt = (const float4*)d_in[2];
  float* out = (float*)d_out;

  u32 k1a, k1b, k2a, k2b, k3a, k3b;
  jax_split3(k1a, k1b, k2a, k2b, k3a, k3b);

  // ws layout: counters(16KB padded slots) | gHistA(4KB) | bufTopA(64KB)
  //            | bufB(512KB) | bufC(512KB) | bufA(16 x 65536 x 8B = 8MB)
  uint8_t* base = (uint8_t*)d_ws;
  u32* counters = (u32*)base;
  u32* gHistA = (u32*)(base + 16384);
  u64* bufTopA = (u64*)(base + 16384 + 4096);
  u64* bufB = (u64*)(base + 16384 + 4096 + (size_t)TOPA_CAP * 8);
  u64* bufC = bufB + (size_t)SHARDS * SHARD_CAP;
  u64* bufA = bufC + (size_t)SHARDS * SHARD_CAP;

  hipMemsetAsync(d_ws, 0, 16384 + 4096, stream);  // counters + gHistA + ticket
  rpn_collect<<<PERSIST, 256, 0, stream>>>(
      props, gt, bufA, bufB, bufC, counters, gHistA, k1a, k1b, k3a, k3b);
  rpn_filterA<<<256, 256, 0, stream>>>(bufA, gHistA, counters, bufTopA);
  rpn_finalize<<<1, 1024, 0, stream>>>(obj, props, gt, bufTopA, bufB, bufC,
                                       counters, out, k2a, k2b);
}

// Round 14
// 95.536 us; speedup vs baseline: 1.2413x; 1.2413x over previous
//
#include <hip/hip_runtime.h>
#include <stdint.h>

// All FP must match XLA's HLO op-for-op: no mul+add contraction.
#pragma clang fp contract(off)

typedef unsigned long long u64;
typedef uint32_t u32;

#define M_PROP 200000u
#define N_GT   128u
#define NM     25600000u

// priority keep-windows (23-bit priorities):
//  B: pos pairs (iou>0.4, ~500k) with m1 >= 2^23-2^15 -> E~1953 kept ==> the
//     true top-128 pos-priority keys are all kept (exact).
//  C: neg pairs (iou<0.1, ~25.1M) with m3 >= 2^23-2^10 -> E~3065 kept.
#define BCUT 8355840u   // 2^23 - 2^15
#define CCUT 8387584u   // 2^23 - 1024
#define IB_POS 0x3ECCCCCDu  // float bits of 0.4f; ib > this <=> iou > 0.4f

#define SHARDS 16u
#define SHARD_CAP 4096u
#define ACAP_SHARD 65536u
#define TOPA_CAP 8192u
#define COMP_CAP 8192u
#define ALIST 512u         // per-wave A-precandidate LDS staging (u32 idx)

#define NBX 782u           // ceil(200000/256)
#define NT_A (NBX * 2u)    // A tiles: 64 gt-rows each
#define NT_ALL (NBX * 6u)  // + C tiles: 32 gt-rows each
#define PERSIST 2048u      // 8 blocks/CU x 256 CUs

// counter slots, each padded to 256B to spread L2 atomic traffic:
// 0..15 = C shards, 16..31 = B shards, 32..47 = A shards, 48 = cntTopA
#define CSLOT(i) counters[(u32)(i) * 64u]

__device__ inline u32 rotl32(u32 x, u32 r) { return __builtin_rotateleft32(x, r); }

// prefix count of set bits below this lane (2 VALU ops)
__device__ inline u32 lane_prefix(u64 mask) {
  return __builtin_amdgcn_mbcnt_hi((u32)(mask >> 32),
                                   __builtin_amdgcn_mbcnt_lo((u32)mask, 0u));
}

// ---------------- threefry2x32 (20 rounds) ----------------
__host__ __device__ inline void tf2x32(u32 k0, u32 k1, u32 x0, u32 x1,
                                       u32& o0, u32& o1) {
  u32 ks0 = k0, ks1 = k1, ks2 = k0 ^ k1 ^ 0x1BD11BDAu;
  x0 += ks0; x1 += ks1;
#ifdef __HIP_DEVICE_COMPILE__
#define TF_R(r) { x0 += x1; x1 = rotl32(x1, r); x1 ^= x0; }
#else
#define TF_R(r) { x0 += x1; x1 = (x1 << r) | (x1 >> (32 - r)); x1 ^= x0; }
#endif
  TF_R(13) TF_R(15) TF_R(26) TF_R(6)
  x0 += ks1; x1 += ks2 + 1u;
  TF_R(17) TF_R(29) TF_R(16) TF_R(24)
  x0 += ks2; x1 += ks0 + 2u;
  TF_R(13) TF_R(15) TF_R(26) TF_R(6)
  x0 += ks0; x1 += ks1 + 3u;
  TF_R(17) TF_R(29) TF_R(16) TF_R(24)
  x0 += ks1; x1 += ks2 + 4u;
  TF_R(13) TF_R(15) TF_R(26) TF_R(6)
  x0 += ks2; x1 += ks0 + 5u;
#undef TF_R
  o0 = x0; o1 = x1;
}

// partitionable threefry: 32 bits for element idx
__device__ inline u32 jax_bits32(u32 ka, u32 kb, u32 idx) {
  u32 a, b; tf2x32(ka, kb, 0u, idx, a, b);
  return a ^ b;
}

static void jax_split3(u32& k1a, u32& k1b, u32& k2a, u32& k2b,
                       u32& k3a, u32& k3b) {
  const u32 K0 = 0u, K1 = 42u;
  tf2x32(K0, K1, 0u, 0u, k1a, k1b);
  tf2x32(K0, K1, 0u, 1u, k2a, k2b);
  tf2x32(K0, K1, 0u, 2u, k3a, k3b);
}

// wave-aggregated append (one atomic per wave per predicate)
__device__ inline u32 wave_append_slot(u32* ctr, bool pred, bool& any) {
  u64 mask = __ballot(pred);
  if (mask == 0ull) { any = false; return 0u; }
  any = true;
  u32 prefix = lane_prefix(mask);
  int leader = __ffsll(mask) - 1;
  u32 base = 0u;
  if ((int)(threadIdx.x & 63u) == leader)
    base = atomicAdd(ctr, (u32)__popcll(mask));
  base = __shfl(base, leader, 64);
  return base + prefix;
}

__device__ inline u32 iouBin(u32 bits) {  // monotone bins over (0.25, 1.0]
  u32 b = (bits - 0x3E800000u) >> 14;
  return b > 1023u ? 1023u : b;
}

// ---------------- K1: persistent fused role-split collection ----------------
// tiles 0..NT_A-1: A-role (64 gt rows); tiles NT_A..: C-role (32 gt rows)
__global__ __launch_bounds__(256, 8) void rpn_collect(
    const float4* __restrict__ props, const float4* __restrict__ gt,
    u64* __restrict__ bufA, u64* __restrict__ bufB, u64* __restrict__ bufC,
    u32* __restrict__ counters, u32* __restrict__ gHistA,
    u32 k1a, u32 k1b, u32 k3a, u32 k3b) {
  __shared__ float4 gtS[64];
  __shared__ float gtAreaS[64];
  __shared__ u32 hA[1024];
  __shared__ u32 listA[4][ALIST];
  const u32 tid = threadIdx.x;
  const u32 lane = tid & 63u;
  const u32 wid = tid >> 6;
  for (u32 i = tid; i < 1024u; i += 256u) hA[i] = 0u;

  for (u32 t = blockIdx.x; t < NT_ALL; t += PERSIST) {
    __syncthreads();  // protect gtS/hA reuse across tiles
    const u32 shard = t & (SHARDS - 1u);
    if (t < NT_A) {
      // ================= A-role: IoU + A/B collection =================
      const u32 bx = t >> 1;
      const u32 gbase = (t & 1u) * 64u;
      for (u32 j = tid; j < 64u; j += 256u) {
        float4 gb = gt[gbase + j];
        gtS[j] = gb;
        gtAreaS[j] = (gb.z - gb.x) * (gb.w - gb.y);
      }
      __syncthreads();
      u32* cntB_g = &CSLOT(16u + shard);
      u32* cntA_g = &CSLOT(32u + shard);
      u64* myBufB = bufB + (size_t)shard * SHARD_CAP;
      u64* myBufA = bufA + (size_t)shard * ACAP_SHARD;

      u32 p = bx * 256u + tid;
      bool active = p < M_PROP;
      float4 pb = make_float4(0.f, 0.f, 0.f, 0.f);
      if (active) pb = props[p];
      float pa = (pb.z - pb.x) * (pb.w - pb.y);
      u32 cntA = 0u;  // wave-uniform

#define PROCESS_A()                                                          \
      {                                                                      \
        for (u32 i = lane; i < cntA; i += 64u) {                             \
          u32 aidx = listA[wid][i];                                          \
          u32 row = aidx / M_PROP;                                           \
          u32 col = aidx - row * M_PROP;                                     \
          float4 pbx = props[col];                                           \
          float4 gbx = gtS[row - gbase];                                     \
          float gax = gtAreaS[row - gbase];                                  \
          float pax = (pbx.z - pbx.x) * (pbx.w - pbx.y);                     \
          float wxx = fminf(gbx.z, pbx.z) - fmaxf(gbx.x, pbx.x);             \
          float wyy = fminf(gbx.w, pbx.w) - fmaxf(gbx.y, pbx.y);             \
          wxx = fmaxf(wxx, 0.0f); wyy = fmaxf(wyy, 0.0f);                    \
          float interx = wxx * wyy;                                          \
          float ioux = interx / (gax + pax - interx);                        \
          u32 ib = __float_as_uint(ioux);                                    \
          bool isA = ioux > 0.25f;                                           \
          if (isA) atomicAdd(&hA[iouBin(ib)], 1u);                           \
          bool anyk;                                                         \
          u32 sk = wave_append_slot(cntA_g, isA, anyk);                      \
          if (isA && sk < ACAP_SHARD)                                        \
            myBufA[sk] = ((u64)ib << 25) | (u64)(0x1FFFFFFu - aidx);         \
          u32 m1 = jax_bits32(k1a, k1b, aidx) >> 9;                          \
          bool keep = isA && (ib > IB_POS) && (m1 >= BCUT);                  \
          bool anyb;                                                         \
          u32 sb2 = wave_append_slot(cntB_g, keep, anyb);                    \
          if (keep && sb2 < SHARD_CAP)                                       \
            myBufB[sb2] = ((u64)m1 << 25) | (u64)(0x1FFFFFFu - (aidx + 128u)); \
        }                                                                    \
        cntA = 0u;                                                           \
      }

      for (u32 gg = 0u; gg < 64u; gg += 4u) {
        bool aa[4];
#pragma unroll
        for (u32 r = 0u; r < 4u; ++r) {
          float4 gb = gtS[gg + r];
          float ga = gtAreaS[gg + r];
          float wx = fminf(gb.z, pb.z) - fmaxf(gb.x, pb.x);
          float wy = fminf(gb.w, pb.w) - fmaxf(gb.y, pb.y);
          wx = fmaxf(wx, 0.0f); wy = fmaxf(wy, 0.0f);
          float inter = wx * wy;
          float uni = ga + pa - inter;
          // conservative superset of iou>0.25 (margin 4e-5 >> fdiv ulp);
          // exact test re-done in PROCESS_A
          aa[r] = active && (inter > 0.2499f * uni);
        }
#pragma unroll
        for (u32 r = 0u; r < 4u; ++r) {
          u64 ma = __ballot(aa[r]);
          if (ma) {
            u32 pfx = lane_prefix(ma);
            if (aa[r]) listA[wid][cntA + pfx] = (gbase + gg + r) * M_PROP + p;
            cntA += (u32)__popcll(ma);
          }
        }
        if (cntA > ALIST - 256u) PROCESS_A();
      }
      PROCESS_A();
#undef PROCESS_A
    } else {
      // ============ C-role: threefry scan, 8 named chains ============
      const u32 ct = t - NT_A;
      const u32 bx = ct >> 2;
      const u32 gbase = (ct & 3u) * 32u;
      for (u32 j = tid; j < 32u; j += 256u) {
        float4 gb = gt[gbase + j];
        gtS[j] = gb;
        gtAreaS[j] = (gb.z - gb.x) * (gb.w - gb.y);
      }
      __syncthreads();
      u32* cntC_g = &CSLOT(shard);
      u64* myBufC = bufC + (size_t)shard * SHARD_CAP;

      u32 p = bx * 256u + tid;
      bool active = p < M_PROP;

      for (u32 gg = 0u; gg < 32u; gg += 8u) {
        const u32 ibase = (gbase + gg) * M_PROP + p;
        // 8 fully-named independent threefry chains (no arrays -> no scratch)
#define TFCH(R) u32 m3_##R; { u32 a_, b_; \
        tf2x32(k3a, k3b, 0u, ibase + (R) * M_PROP, a_, b_); \
        m3_##R = (a_ ^ b_) >> 9; }
        TFCH(0) TFCH(1) TFCH(2) TFCH(3) TFCH(4) TFCH(5) TFCH(6) TFCH(7)
#undef TFCH
        bool pre0 = m3_0 >= CCUT, pre1 = m3_1 >= CCUT;
        bool pre2 = m3_2 >= CCUT, pre3 = m3_3 >= CCUT;
        bool pre4 = m3_4 >= CCUT, pre5 = m3_5 >= CCUT;
        bool pre6 = m3_6 >= CCUT, pre7 = m3_7 >= CCUT;
        bool anyp = pre0 | pre1 | pre2 | pre3 | pre4 | pre5 | pre6 | pre7;
        if (__ballot(anyp)) {  // rare: ~6% of groups -> lazy exact IoU
          float4 pbx = make_float4(0.f, 0.f, 0.f, 0.f);
          if (active) pbx = props[p];
          float pax = (pbx.z - pbx.x) * (pbx.w - pbx.y);
#define CRARE(R)                                                             \
          {                                                                  \
            float4 gb = gtS[gg + (R)];                                       \
            float ga = gtAreaS[gg + (R)];                                    \
            float wx = fminf(gb.z, pbx.z) - fmaxf(gb.x, pbx.x);              \
            float wy = fminf(gb.w, pbx.w) - fmaxf(gb.y, pbx.y);              \
            wx = fmaxf(wx, 0.0f); wy = fmaxf(wy, 0.0f);                      \
            float inter = wx * wy;                                           \
            float iouX = inter / (ga + pax - inter);                         \
            bool cc = active && pre##R && (iouX < 0.1f);                     \
            bool any_;                                                       \
            u32 s = wave_append_slot(cntC_g, cc, any_);                      \
            if (cc && s < SHARD_CAP)                                         \
              myBufC[s] = ((u64)m3_##R << 25) |                              \
                          (u64)(0x1FFFFFFu - (ibase + (R) * M_PROP));        \
          }
          CRARE(0) CRARE(1) CRARE(2) CRARE(3)
          CRARE(4) CRARE(5) CRARE(6) CRARE(7)
#undef CRARE
        }
      }
    }
  }

  __syncthreads();
  for (u32 b = tid; b < 1024u; b += 256u) {
    u32 v = hA[b];
    if (v) atomicAdd(&gHistA[b], v);
  }
}

// ---------------- K2: per-wave shfl cut + filter stored A-keys ----------------
__global__ __launch_bounds__(256) void rpn_filterA(
    const u64* __restrict__ bufA, const u32* __restrict__ gHistA,
    u32* __restrict__ counters, u64* __restrict__ bufTopA) {
  const u32 tid = threadIdx.x;
  const u32 lane = tid & 63u;
  // each wave redundantly computes cut = max b with suffix(hist[b..]) >= 128
  u32 loc[16]; u32 t = 0u;
  const u32 bbase = lane * 16u;
#pragma unroll
  for (u32 j = 0u; j < 16u; ++j) { loc[j] = gHistA[bbase + j]; t += loc[j]; }
  u32 suf = t;
  for (u32 off = 1u; off < 64u; off <<= 1u) {
    u32 o = __shfl_down(suf, off, 64);
    if (lane + off < 64u) suf += o;
  }
  u32 cum = suf - t;   // sum over lanes > this one
  u32 cand = 0u; bool found = false;
#pragma unroll
  for (int j = 15; j >= 0; --j) {
    cum += loc[j];
    if (!found && cum >= 128u) { cand = bbase + (u32)j; found = true; }
  }
  for (u32 off = 1u; off < 64u; off <<= 1u) {
    u32 o = __shfl_xor(cand, off, 64);
    cand = o > cand ? o : cand;
  }
  const u32 cut = cand;
  // 256 blocks = 16 shards x 16 chunks, coalesced within each block
  const u32 sh = blockIdx.x & (SHARDS - 1u);
  const u32 chunk = blockIdx.x >> 4;
  u32 n = CSLOT(32u + sh); n = n < ACAP_SHARD ? n : ACAP_SHARD;
  const u64* sb = bufA + (size_t)sh * ACAP_SHARD;
  for (u32 i = chunk * 256u + tid; i < n; i += 16u * 256u) {
    u64 k = sb[i];
    bool keep = iouBin((u32)(k >> 25)) >= cut;
    bool any;
    u32 s = wave_append_slot(&CSLOT(48), keep, any);
    if (keep && s < TOPA_CAP) bufTopA[s] = k;
  }
}

// ---------------- K3: rank-select + loss ----------------
// 8-slot exact top-128 (desc) of nc distinct keys, nc <= 8192.
__device__ inline void rank_select(const u64* cand, u32 nc, u64* selKey) {
  const u32 tid = threadIdx.x;
  if (tid < 128u) selKey[tid] = 0ull;
  u64 k[8]; u32 r[8];
#pragma unroll
  for (int j = 0; j < 8; ++j) {
    u32 i = tid + (u32)j * 1024u;
    k[j] = (i < nc) ? cand[i] : 0ull;
    r[j] = 0u;
  }
  __syncthreads();
  for (u32 i = 0u; i < nc; ++i) {
    u64 v = cand[i];
#pragma unroll
    for (int j = 0; j < 8; ++j) r[j] += (v > k[j]) ? 1u : 0u;
  }
#pragma unroll
  for (int j = 0; j < 8; ++j) {
    u32 i = tid + (u32)j * 1024u;
    if (i < nc && r[j] < 128u) selKey[r[j]] = k[j];
  }
  __syncthreads();
}

// 1-slot exact top-128 of nc distinct keys, nc <= 1024.
__device__ inline void rank_select2(const u64* cand, u32 nc, u64* selKey) {
  const u32 tid = threadIdx.x;
  if (tid < 128u) selKey[tid] = 0ull;
  u64 mine = (tid < nc) ? cand[tid] : 0ull;
  __syncthreads();
  u32 r = 0u;
  for (u32 i = 0u; i < nc; ++i) r += (cand[i] > mine) ? 1u : 0u;
  if (tid < nc && r < 128u) selKey[r] = mine;
  __syncthreads();
}

__device__ inline float sl1(float d) {
  float ad = fabsf(d);
  return (ad < 1.0f) ? 0.5f * d * d : ad - 0.5f;
}

__global__ __launch_bounds__(1024) void rpn_finalize(
    const float* __restrict__ obj, const float4* __restrict__ props,
    const float4* __restrict__ gt,
    const u64* __restrict__ bufTopA,
    const u64* __restrict__ bufB, const u64* __restrict__ bufC,
    const u32* __restrict__ counters, float* __restrict__ out,
    u32 k2a, u32 k2b) {
  __shared__ u64 keyBuf[COMP_CAP];
  __shared__ u64 keyBuf2[1024];
  __shared__ u64 selKey[128];
  __shared__ u32 bestIdx[128];
  __shared__ u32 hist64[64];
  __shared__ float pr[16];
  __shared__ u32 s_cnt, s_cnt2, s_cutLo;
  __shared__ float s_reg, s_bcep;

  const u32 tid = threadIdx.x;
  const u32 lane = tid & 63u;
  const u32 wid = tid >> 6u;

  // ===== Phase 1: best_idx = top-128 of flat IoU (desc, ties idx asc) =====
  u32 nT = CSLOT(48); nT = nT < TOPA_CAP ? nT : TOPA_CAP;
  for (u32 i = tid; i < nT; i += 1024u) keyBuf[i] = bufTopA[i];
  __syncthreads();
  if (nT <= 1024u) rank_select2(keyBuf, nT, selKey);
  else rank_select(keyBuf, nT, selKey);
  if (tid < 128u) {
    u64 k = selKey[tid];
    bestIdx[tid] = (k == 0ull) ? 0u : (0x1FFFFFFu - (u32)(k & 0x1FFFFFFu));
  }
  __syncthreads();

  // ===== Phase 2: positives = top-128 of [best_prio(128) ++ pos_prio] =====
  if (tid == 0u) { s_cnt = 128u; s_cnt2 = 0u; }
  if (tid < 64u) hist64[tid] = 0u;
  __syncthreads();
  if (tid < 128u) {
    u32 m2 = jax_bits32(k2a, k2b, tid) >> 9;
    keyBuf[tid] = ((u64)m2 << 25) | (u64)(0x1FFFFFFu - tid);
    if (m2 >= BCUT) atomicAdd(&hist64[(m2 - BCUT) >> 9], 1u);
  }
  {  // wave-parallel shard load: wave w owns shard w
    u32 n = CSLOT(16u + wid); n = n < SHARD_CAP ? n : SHARD_CAP;
    const u64* sb = bufB + (size_t)wid * SHARD_CAP;
    for (u32 i = lane; i < n; i += 64u) {
      u64 k = sb[i];
      bool any;
      u32 s = wave_append_slot(&s_cnt, true, any);
      if (s < COMP_CAP) keyBuf[s] = k;
      atomicAdd(&hist64[((u32)(k >> 25) - BCUT) >> 9], 1u);
    }
  }
  __syncthreads();
  u32 nc = s_cnt < COMP_CAP ? s_cnt : COMP_CAP;
  if (wid == 0u) {  // single-wave 64-bin suffix cut, no barriers
    u32 suf = hist64[lane];
    for (u32 off = 1u; off < 64u; off <<= 1u) {
      u32 o = __shfl_down(suf, off, 64);
      if (lane + off < 64u) suf += o;
    }
    u64 ok = __ballot(suf >= 128u);
    u32 cutLo = 0u;
    if (ok) cutLo = BCUT + ((63u - (u32)__clzll(ok)) << 9);
    if (lane == 0u) s_cutLo = cutLo;
  }
  __syncthreads();
  {
    u64 cutKey = ((u64)s_cutLo) << 25;
    for (u32 i = tid; i < nc; i += 1024u) {
      u64 k = keyBuf[i];
      if (k >= cutKey) {
        u32 s = atomicAdd(&s_cnt2, 1u);
        if (s < 1024u) keyBuf2[s] = k;
      }
    }
  }
  __syncthreads();
  u32 ns = s_cnt2;
  if (ns <= 1024u) rank_select2(keyBuf2, ns, selKey);
  else rank_select(keyBuf, nc, selKey);

  float locReg = 0.0f, locBce = 0.0f;
  if (tid < 128u) {
    u64 k = selKey[tid];
    if (k != 0ull) {
      u32 c = 0x1FFFFFFu - (u32)(k & 0x1FFFFFFu);
      u32 pair = (c < 128u) ? bestIdx[c] : (c - 128u);
      if (pair < NM) {
        u32 row = pair / M_PROP, col = pair % M_PROP;
        float4 prb = props[col];
        float4 gb = gt[row];
        locReg = sl1(prb.x - gb.x) + sl1(prb.y - gb.y) +
                 sl1(prb.z - gb.z) + sl1(prb.w - gb.w);
        float l = obj[col];
        locBce = fmaxf(l, 0.0f) - l + log1pf(expf(-fabsf(l)));
      }
    }
  }
  {  // shfl reductions (only waves 0-1 carry data)
    float v = locReg;
    for (u32 off = 32u; off > 0u; off >>= 1u) v += __shfl_xor(v, off, 64);
    if (lane == 0u) pr[wid] = v;
    __syncthreads();
    if (tid == 0u) {
      float s = 0.0f;
#pragma unroll
      for (u32 w = 0u; w < 16u; ++w) s += pr[w];
      s_reg = s;
    }
    __syncthreads();
    v = locBce;
    for (u32 off = 32u; off > 0u; off >>= 1u) v += __shfl_xor(v, off, 64);
    if (lane == 0u) pr[wid] = v;
    __syncthreads();
    if (tid == 0u) {
      float s = 0.0f;
#pragma unroll
      for (u32 w = 0u; w < 16u; ++w) s += pr[w];
      s_bcep = s;
    }
    __syncthreads();
  }

  // ===== Phase 3: negatives = top-128 of neg_prio =====
  if (tid == 0u) { s_cnt = 0u; s_cnt2 = 0u; }
  if (tid < 64u) hist64[tid] = 0u;
  __syncthreads();
  {  // wave-parallel shard load
    u32 n = CSLOT(wid); n = n < SHARD_CAP ? n : SHARD_CAP;
    const u64* sb = bufC + (size_t)wid * SHARD_CAP;
    for (u32 i = lane; i < n; i += 64u) {
      u64 k = sb[i];
      bool any;
      u32 s = wave_append_slot(&s_cnt, true, any);
      if (s < COMP_CAP) keyBuf[s] = k;
      atomicAdd(&hist64[((u32)(k >> 25) - CCUT) >> 4], 1u);
    }
  }
  __syncthreads();
  nc = s_cnt < COMP_CAP ? s_cnt : COMP_CAP;
  if (wid == 0u) {
    u32 suf = hist64[lane];
    for (u32 off = 1u; off < 64u; off <<= 1u) {
      u32 o = __shfl_down(suf, off, 64);
      if (lane + off < 64u) suf += o;
    }
    u64 ok = __ballot(suf >= 128u);
    u32 cutLo = 0u;
    if (ok) cutLo = CCUT + ((63u - (u32)__clzll(ok)) << 4);
    if (lane == 0u) s_cutLo = cutLo;
  }
  __syncthreads();
  {
    u64 cutKey = ((u64)s_cutLo) << 25;
    for (u32 i = tid; i < nc; i += 1024u) {
      u64 k = keyBuf[i];
      if (k >= cutKey) {
        u32 s = atomicAdd(&s_cnt2, 1u);
        if (s < 1024u) keyBuf2[s] = k;
      }
    }
  }
  __syncthreads();
  ns = s_cnt2;
  if (ns <= 1024u) rank_select2(keyBuf2, ns, selKey);
  else rank_select(keyBuf, nc, selKey);

  float locBceN = 0.0f;
  if (tid < 128u) {
    u64 k = selKey[tid];
    if (k != 0ull) {
      u32 idx = 0x1FFFFFFu - (u32)(k & 0x1FFFFFFu);
      u32 col = idx % M_PROP;
      float l = obj[col];
      locBceN = fmaxf(l, 0.0f) + log1pf(expf(-fabsf(l)));
    }
  }
  {
    float v = locBceN;
    for (u32 off = 32u; off > 0u; off >>= 1u) v += __shfl_xor(v, off, 64);
    if (lane == 0u) pr[wid] = v;
    __syncthreads();
    if (tid == 0u) {
      float s = 0.0f;
#pragma unroll
      for (u32 w = 0u; w < 16u; ++w) s += pr[w];
      float cls = (s_bcep + s) / 256.0f;
      float reg = s_reg / 512.0f;
      out[0] = cls + 10.0f * reg;
    }
  }
}

extern "C" void kernel_launch(void* const* d_in, const int* in_sizes, int n_in,
                              void* d_out, int out_size, void* d_ws, size_t ws_size,
                              hipStream_t stream) {
  (void)in_sizes; (void)n_in; (void)out_size; (void)ws_size;
  const float* obj = (const float*)d_in[0];
  const float4* props = (const float4*)d_in[1];
  const float4* gt = (const float4*)d_in[2];
  float* out = (float*)d_out;

  u32 k1a, k1b, k2a, k2b, k3a, k3b;
  jax_split3(k1a, k1b, k2a, k2b, k3a, k3b);

  // ws layout: counters(16KB padded slots) | gHistA(4KB) | bufTopA(64KB)
  //            | bufB(512KB) | bufC(512KB) | bufA(16 x 65536 x 8B = 8MB)
  uint8_t* base = (uint8_t*)d_ws;
  u32* counters = (u32*)base;
  u32* gHistA = (u32*)(base + 16384);
  u64* bufTopA = (u64*)(base + 16384 + 4096);
  u64* bufB = (u64*)(base + 16384 + 4096 + (size_t)TOPA_CAP * 8);
  u64* bufC = bufB + (size_t)SHARDS * SHARD_CAP;
  u64* bufA = bufC + (size_t)SHARDS * SHARD_CAP;

  hipMemsetAsync(d_ws, 0, 16384 + 4096, stream);  // counters + gHistA
  rpn_collect<<<PERSIST, 256, 0, stream>>>(
      props, gt, bufA, bufB, bufC, counters, gHistA, k1a, k1b, k3a, k3b);
  rpn_filterA<<<256, 256, 0, stream>>>(bufA, gHistA, counters, bufTopA);
  rpn_finalize<<<1, 1024, 0, stream>>>(obj, props, gt, bufTopA, bufB, bufC,
                                       counters, out, k2a, k2b);
}